// Round 9
// baseline (348.623 us; speedup 1.0000x reference)
//
#include <hip/hip_runtime.h>

typedef unsigned int u32;
typedef unsigned short u16;
typedef u16 u16x4 __attribute__((ext_vector_type(4)));
typedef u16 u16x8 __attribute__((ext_vector_type(8)));
typedef u32 u32x2 __attribute__((ext_vector_type(2)));
typedef u32 u32x4 __attribute__((ext_vector_type(4)));
typedef __bf16 bf16x8 __attribute__((ext_vector_type(8)));
typedef float f32x4 __attribute__((ext_vector_type(4)));

#define LDK 136   // padded LDS leading dim: row stride 68 dwords == 4-bank shift/row
// Chunk XOR on top of pad (bits 5-6 of col only; all accesses are >=4-elem aligned
// runs inside one 16B chunk, so runs stay contiguous and inside the row).
#define TIDX(r, c) ((r) * LDK + ((c) ^ (((r) & 3) << 5)))
#define MFMA(a, b, c) __builtin_amdgcn_mfma_f32_16x16x32_bf16(a, b, c, 0, 0, 0)

__device__ __forceinline__ u16 f2b(float f) {
  u32 u = __builtin_bit_cast(u32, f);
  u = (u + 0x7fffu + ((u >> 16) & 1u)) >> 16;
  return (u16)u;
}
__device__ __forceinline__ float b2f(u16 h) {
  u32 u = ((u32)h) << 16;
  return __builtin_bit_cast(float, u);
}
__device__ __forceinline__ u32 pk2(float lo, float hi) {
  return (u32)f2b(lo) | ((u32)f2b(hi) << 16);
}

// ---------------- weight prep: wT[m][d][c] = bf16(W_m[c][d]) ----------------
__global__ void wprep(const float* __restrict__ Wq, const float* __restrict__ Wk,
                      const float* __restrict__ Wv, const float* __restrict__ Ws,
                      u16* __restrict__ wT) {
  const float* srcs[4] = {Wq, Wk, Wv, Ws};
  const float* s = srcs[blockIdx.x];
  u16* d = wT + (size_t)blockIdx.x * 16384;
  for (int idx = threadIdx.x; idx < 16384; idx += 256) {
    int i = idx >> 7, j = idx & 127;   // W[i=c_in][j=c_out]
    d[j * 128 + i] = f2b(s[idx]);
  }
}

// ---------------- QKV: direct-from-global A-fragments ----------------
// Wave owns a 32-row w-strip and ALL c_out: A-fragments are wave-private, loaded
// straight from global fp32 (16 rows x 64B fully-used segments; same bytes as the
// old stage) and converted once in-register. No stage phase, no A ds_reads, one
// fewer barrier; loads interleave with MFMA. B (wT) is L1/L2-hot. Bounce + store
// unchanged (write-ideal, proven r7). XCD grouping as r7.
__global__ __launch_bounds__(256, 4)
void qkv_kernel(const float* __restrict__ x1, const float* __restrict__ x2,
                const u16* __restrict__ wT,
                u16* __restrict__ q_t, u16* __restrict__ k_t, u16* __restrict__ v_t) {
  __shared__ u16 Xs[128 * LDK];   // bounce tile [c][w]

  const int t = threadIdx.x;
  const int bid = blockIdx.x;
  const int xs = bid & 7;
  const int m = (bid >> 3) % 3;            // 0=q, 1=k, 2=v
  const int bh = (bid / 24) * 8 + xs;      // each (bh,m) exactly once
  const int b = bh >> 7, h = bh & 127;
  const size_t pixbase = (size_t)bh * 16384;
  const size_t obase = (size_t)b * 2097152 + (size_t)h * 128;

  const float* xin = (m == 2) ? x2 : x1;
  u16* dst = (m == 0) ? q_t : (m == 1) ? k_t : v_t;

  const int lane = t & 63, wave = t >> 6;
  const int lrow = lane & 15, lq = lane >> 4;
  const u16* wb = wT + (size_t)m * 16384;

  // wave's A rows: w = wave*32 + mt*16 + lrow (mt = 0,1)
  const float* arow0 = &xin[pixbase + (size_t)(wave * 32 + lrow) * 128];
  const float* arow1 = arow0 + 16 * 128;

  f32x4 acc[2][8];
#pragma unroll
  for (int mt = 0; mt < 2; ++mt)
#pragma unroll
    for (int ns = 0; ns < 8; ++ns) acc[mt][ns] = (f32x4){0.f, 0.f, 0.f, 0.f};

#pragma unroll
  for (int kk = 0; kk < 4; ++kk) {
    int ko = kk * 32 + lq * 8;
    // A-fragments direct from global fp32, cvt in-register
    f32x4 u00 = *(const f32x4*)&arow0[ko];
    f32x4 u01 = *(const f32x4*)&arow0[ko + 4];
    f32x4 u10 = *(const f32x4*)&arow1[ko];
    f32x4 u11 = *(const f32x4*)&arow1[ko + 4];
    u16x8 pa0, pa1;
#pragma unroll
    for (int i = 0; i < 4; ++i) {
      pa0[i] = f2b(u00[i]); pa0[4 + i] = f2b(u01[i]);
      pa1[i] = f2b(u10[i]); pa1[4 + i] = f2b(u11[i]);
    }
    bf16x8 a0 = __builtin_bit_cast(bf16x8, pa0);
    bf16x8 a1 = __builtin_bit_cast(bf16x8, pa1);
#pragma unroll
    for (int ns = 0; ns < 8; ++ns) {
      bf16x8 bfrag = *(const bf16x8*)&wb[(ns * 16 + lrow) * 128 + ko];
      acc[0][ns] = MFMA(a0, bfrag, acc[0][ns]);
      acc[1][ns] = MFMA(a1, bfrag, acc[1][ns]);
    }
  }

  // bounce: relu(acc) -> Xs[c][w]  (c = ns*16+lrow, w = wave*32 + mt*16 + lq*4 + r)
#pragma unroll
  for (int mt = 0; mt < 2; ++mt) {
    int w0i = wave * 32 + mt * 16 + lq * 4;
#pragma unroll
    for (int ns = 0; ns < 8; ++ns) {
      int c = ns * 16 + lrow;
      u32x2 p;
      p[0] = pk2(fmaxf(acc[mt][ns][0], 0.f), fmaxf(acc[mt][ns][1], 0.f));
      p[1] = pk2(fmaxf(acc[mt][ns][2], 0.f), fmaxf(acc[mt][ns][3], 0.f));
      *(u32x2*)&Xs[TIDX(c, w0i)] = p;
    }
  }
  __syncthreads();

  // coalesced store: per j, 16 full c-rows (256B contiguous each)
#pragma unroll
  for (int j = 0; j < 8; ++j) {
    int c = j * 16 + (t >> 4), wv = (t & 15) * 8;
    *(u16x8*)&dst[obase + (size_t)c * 16384 + wv] = *(const u16x8*)&Xs[TIDX(c, wv)];
  }
}

// ---------------- attention: per (b,c); S^T = K Q^T, softmax over g, O^T = V^T P^T --
// Single LDS buffer (K -> V^T -> O bounce). P in registers (packed bf16),
// redistributed to PV B-fragments via shfl (mapping verified r4).
__global__ __launch_bounds__(256, 3)
void attn_kernel(u16* __restrict__ q_t, const u16* __restrict__ k_t,
                 const u16* __restrict__ v_t, const float* __restrict__ scale_p) {
  __shared__ u16 Ks[128 * LDK];

  const int t = threadIdx.x;
  const size_t base = (size_t)blockIdx.x * 16384;

  const int lane = t & 63, wave = t >> 6;
  const int lrow = lane & 15, lq = lane >> 4;
  const int hstrip = wave * 32;
  const float scl = scale_p[0];

  // Q fragments (per-wave-private rows) straight from global
  bf16x8 q0[4], q1[4];
#pragma unroll
  for (int kk = 0; kk < 4; ++kk) {
    int ko = kk * 32 + lq * 8;
    q0[kk] = *(const bf16x8*)&q_t[base + (hstrip + lrow) * 128 + ko];
    q1[kk] = *(const bf16x8*)&q_t[base + (hstrip + 16 + lrow) * 128 + ko];
  }
  // K into LDS (coalesced, swizzled)
#pragma unroll
  for (int j = 0; j < 8; ++j) {
    int lin = j * 256 + t;
    int r = lin >> 4, c0 = (lin & 15) << 3;
    *(u16x8*)&Ks[TIDX(r, c0)] = *(const u16x8*)&k_t[base + lin * 8];
  }
  __syncthreads();

  // S^T[g][h]: A = Ks rows g, B = Q frags
  f32x4 acc[8][2];
#pragma unroll
  for (int mt = 0; mt < 8; ++mt) {
    acc[mt][0] = (f32x4){0.f, 0.f, 0.f, 0.f};
    acc[mt][1] = (f32x4){0.f, 0.f, 0.f, 0.f};
  }
#pragma unroll
  for (int kk = 0; kk < 4; ++kk) {
    int ko = kk * 32 + lq * 8;
#pragma unroll
    for (int mt = 0; mt < 8; ++mt) {
      bf16x8 a = *(const bf16x8*)&Ks[TIDX(mt * 16 + lrow, ko)];
      acc[mt][0] = MFMA(a, q0[kk], acc[mt][0]);
      acc[mt][1] = MFMA(a, q1[kk], acc[mt][1]);
    }
  }

  // V loads issued now (coalesced 256B runs); latency hides under softmax+pack
  const int w0v = (t & 15) * 8, g0 = (t >> 4) * 8;
  u16x8 vv[8];
#pragma unroll
  for (int i = 0; i < 8; ++i)
    vv[i] = *(const u16x8*)&v_t[base + (size_t)(g0 + i) * 128 + w0v];

  // softmax over g: per-lane 32 values + quad combine via shfl_xor 16/32
  float inv[2];
#pragma unroll
  for (int nt = 0; nt < 2; ++nt) {
    float mx = -1e30f;
#pragma unroll
    for (int mt = 0; mt < 8; ++mt)
#pragma unroll
      for (int r = 0; r < 4; ++r) {
        acc[mt][nt][r] *= scl;
        mx = fmaxf(mx, acc[mt][nt][r]);
      }
    mx = fmaxf(mx, __shfl_xor(mx, 16));
    mx = fmaxf(mx, __shfl_xor(mx, 32));
    float s = 0.f;
#pragma unroll
    for (int mt = 0; mt < 8; ++mt)
#pragma unroll
      for (int r = 0; r < 4; ++r) {
        float e = __expf(acc[mt][nt][r] - mx);
        acc[mt][nt][r] = e;
        s += e;
      }
    s += __shfl_xor(s, 16);
    s += __shfl_xor(s, 32);
    inv[nt] = 1.f / s;
  }

  // pack P (with 1/sum folded) into registers: pk[mt][nt][pair]
  u32 pk[8][2][2];
#pragma unroll
  for (int mt = 0; mt < 8; ++mt)
#pragma unroll
    for (int nt = 0; nt < 2; ++nt) {
      pk[mt][nt][0] = pk2(acc[mt][nt][0] * inv[nt], acc[mt][nt][1] * inv[nt]);
      pk[mt][nt][1] = pk2(acc[mt][nt][2] * inv[nt], acc[mt][nt][3] * inv[nt]);
    }
  __syncthreads();   // all S-MFMA reads of Ks complete -> K dead

  // V^T into Ks (register 8x8 transpose, static indexing only)
#pragma unroll
  for (int j = 0; j < 8; ++j) {
    u16x8 tv;
#pragma unroll
    for (int i = 0; i < 8; ++i) tv[i] = vv[i][j];
    *(u16x8*)&Ks[TIDX(w0v + j, g0)] = tv;
  }
  __syncthreads();

  // O^T[w][h]: A = Ks(V^T) rows w, B = P from registers via shfl redistribution
  const int s01 = lrow + 32 * (lq & 1);
  const int s23 = s01 + 16;
  const bool hi = (lq & 2);
#pragma unroll
  for (int kk = 0; kk < 4; ++kk) {
    int ko = kk * 32 + lq * 8;
    u32x4 bd[2];
#pragma unroll
    for (int nt = 0; nt < 2; ++nt) {
      u32 a0 = pk[2 * kk][nt][0], a1 = pk[2 * kk][nt][1];
      u32 c0 = pk[2 * kk + 1][nt][0], c1 = pk[2 * kk + 1][nt][1];
      u32 l0 = (u32)__shfl((int)a0, s01), h0 = (u32)__shfl((int)c0, s01);
      u32 l1 = (u32)__shfl((int)a1, s01), h1 = (u32)__shfl((int)c1, s01);
      u32 l2 = (u32)__shfl((int)a0, s23), h2 = (u32)__shfl((int)c0, s23);
      u32 l3 = (u32)__shfl((int)a1, s23), h3 = (u32)__shfl((int)c1, s23);
      bd[nt][0] = hi ? h0 : l0;
      bd[nt][1] = hi ? h1 : l1;
      bd[nt][2] = hi ? h2 : l2;
      bd[nt][3] = hi ? h3 : l3;
    }
    bf16x8 bb0 = __builtin_bit_cast(bf16x8, bd[0]);
    bf16x8 bb1 = __builtin_bit_cast(bf16x8, bd[1]);
    if (kk == 0) {
#pragma unroll
      for (int mt = 0; mt < 8; ++mt) {
        acc[mt][0] = (f32x4){0.f, 0.f, 0.f, 0.f};
        acc[mt][1] = (f32x4){0.f, 0.f, 0.f, 0.f};
      }
    }
#pragma unroll
    for (int mt = 0; mt < 8; ++mt) {
      bf16x8 a = *(const bf16x8*)&Ks[TIDX(mt * 16 + lrow, ko)];
      acc[mt][0] = MFMA(a, bb0, acc[mt][0]);
      acc[mt][1] = MFMA(a, bb1, acc[mt][1]);
    }
  }
  __syncthreads();   // PV reads of Ks done -> reuse as O bounce tile

  // bounce O -> Ks[h][w], then fully-contiguous store
#pragma unroll
  for (int mt = 0; mt < 8; ++mt) {
    int w0i = mt * 16 + lq * 4;
#pragma unroll
    for (int nt = 0; nt < 2; ++nt) {
      int hh = hstrip + nt * 16 + lrow;
      u32x2 p;
      p[0] = pk2(acc[mt][nt][0], acc[mt][nt][1]);
      p[1] = pk2(acc[mt][nt][2], acc[mt][nt][3]);
      *(u32x2*)&Ks[TIDX(hh, w0i)] = p;
    }
  }
  __syncthreads();
#pragma unroll
  for (int j = 0; j < 8; ++j) {
    int hh = j * 16 + (t >> 4), wv = (t & 15) * 8;
    *(u16x8*)&q_t[base + hh * 128 + wv] = *(const u16x8*)&Ks[TIDX(hh, wv)];
  }
}

// ---------------- final: s = o @ Ws + bs; sigmoid; BN; out = x1 + x2*g (fp32) -------
__global__ __launch_bounds__(256, 4)
void final_kernel(const u16* __restrict__ o_t, const u16* __restrict__ wsT,
                  const float* __restrict__ x1, const float* __restrict__ x2,
                  const float* __restrict__ bs, const float* __restrict__ gamma,
                  const float* __restrict__ beta, const float* __restrict__ mu,
                  const float* __restrict__ var, float* __restrict__ out) {
  __shared__ u16 Os[128 * LDK];   // o^T tile [w][c] (swizzled)
  __shared__ float bnA[128], bnB[128], bsf[128];

  const int t = threadIdx.x;
  const int bh = blockIdx.x;
  const int b = bh >> 7, h = bh & 127;
  const size_t obase = (size_t)b * 2097152 + (size_t)h * 128;
  const size_t pixbase = (size_t)bh * 16384;

  if (t < 128) {
    float a = gamma[t] * rsqrtf(var[t] + 1e-3f);
    bnA[t] = a;
    bnB[t] = beta[t] - mu[t] * a;
    bsf[t] = bs[t];
  }
  {  // coalesced transpose-load o tile -> Os[w][c] (static indexing only)
    int cb = (t >> 4) * 8, w0 = (t & 15) * 8;
    u16 ov[8][8];
#pragma unroll
    for (int i = 0; i < 8; ++i)
      *(u16x8*)&ov[i][0] = *(const u16x8*)&o_t[obase + (size_t)(cb + i) * 16384 + w0];
#pragma unroll
    for (int j = 0; j < 8; ++j) {
      u16x8 tv;
#pragma unroll
      for (int i = 0; i < 8; ++i) tv[i] = ov[i][j];
      *(u16x8*)&Os[TIDX(w0 + j, cb)] = tv;
    }
  }
  __syncthreads();

  const int lane = t & 63, wave = t >> 6;
  const int lrow = lane & 15, lq = lane >> 4;
  const int wstrip = wave * 32;

  // D[d][w] = sum_c WsT[d][c] * Os[w][c]; A fragments straight from global (L2-hot)
  f32x4 acc[8][2];
#pragma unroll
  for (int mt = 0; mt < 8; ++mt) {
    acc[mt][0] = (f32x4){0.f, 0.f, 0.f, 0.f};
    acc[mt][1] = (f32x4){0.f, 0.f, 0.f, 0.f};
  }
#pragma unroll
  for (int kk = 0; kk < 4; ++kk) {
    int ko = kk * 32 + lq * 8;
    bf16x8 b0 = *(const bf16x8*)&Os[TIDX(wstrip + lrow, ko)];
    bf16x8 b1 = *(const bf16x8*)&Os[TIDX(wstrip + 16 + lrow, ko)];
#pragma unroll
    for (int mt = 0; mt < 8; ++mt) {
      bf16x8 a = *(const bf16x8*)&wsT[(mt * 16 + lrow) * 128 + ko];
      acc[mt][0] = MFMA(a, b0, acc[mt][0]);
      acc[mt][1] = MFMA(a, b1, acc[mt][1]);
    }
  }

  // fused epilogue: sigmoid + BN + gated residual, direct coalesced f32x4 I/O
#pragma unroll
  for (int mt = 0; mt < 8; ++mt) {
    int d0 = mt * 16 + lq * 4;
    f32x4 A4 = *(const f32x4*)&bnA[d0];
    f32x4 B4 = *(const f32x4*)&bnB[d0];
    f32x4 S4 = *(const f32x4*)&bsf[d0];
#pragma unroll
    for (int nt = 0; nt < 2; ++nt) {
      int w = wstrip + nt * 16 + lrow;
      size_t off = pixbase + (size_t)w * 128 + d0;
      f32x4 a1v = *(const f32x4*)&x1[off];
      f32x4 a2v = *(const f32x4*)&x2[off];
      f32x4 r;
#pragma unroll
      for (int r4 = 0; r4 < 4; ++r4) {
        float sv = acc[mt][nt][r4] + S4[r4];
        float sg = 1.f / (1.f + __expf(-sv));
        float g = A4[r4] * sg + B4[r4];
        r[r4] = a1v[r4] + a2v[r4] * g;
      }
      *(f32x4*)&out[off] = r;
    }
  }
}

extern "C" void kernel_launch(void* const* d_in, const int* in_sizes, int n_in,
                              void* d_out, int out_size, void* d_ws, size_t ws_size,
                              hipStream_t stream) {
  const float* x1 = (const float*)d_in[0];
  const float* x2 = (const float*)d_in[1];
  const float* Wq = (const float*)d_in[2];
  const float* Wk = (const float*)d_in[3];
  const float* Wv = (const float*)d_in[4];
  const float* Ws = (const float*)d_in[5];
  const float* bs = (const float*)d_in[6];
  const float* scale = (const float*)d_in[7];
  const float* gamma = (const float*)d_in[8];
  const float* beta = (const float*)d_in[9];
  const float* mu = (const float*)d_in[10];
  const float* var = (const float*)d_in[11];
  float* outp = (float*)d_out;

  // workspace (bf16 elems): q_t | k_t | v_t : [B][C][H][W], then 4 transposed weights
  u16* q_t = (u16*)d_ws;
  u16* k_t = q_t + 16777216;
  u16* v_t = k_t + 16777216;
  u16* wT = v_t + 16777216;  // 4 * 16384

  wprep<<<dim3(4), dim3(256), 0, stream>>>(Wq, Wk, Wv, Ws, wT);
  qkv_kernel<<<dim3(3072), dim3(256), 0, stream>>>(x1, x2, wT, q_t, k_t, v_t);
  attn_kernel<<<dim3(1024), dim3(256), 0, stream>>>(q_t, k_t, v_t, scale);
  final_kernel<<<dim3(1024), dim3(256), 0, stream>>>(q_t, wT + 3 * 16384, x1, x2, bs,
                                                     gamma, beta, mu, var, outp);
}

// Round 10
// 324.716 us; speedup vs baseline: 1.0736x; 1.0736x over previous
//
#include <hip/hip_runtime.h>

typedef unsigned int u32;
typedef unsigned short u16;
typedef u16 u16x4 __attribute__((ext_vector_type(4)));
typedef u16 u16x8 __attribute__((ext_vector_type(8)));
typedef u32 u32x2 __attribute__((ext_vector_type(2)));
typedef u32 u32x4 __attribute__((ext_vector_type(4)));
typedef __bf16 bf16x8 __attribute__((ext_vector_type(8)));
typedef float f32x4 __attribute__((ext_vector_type(4)));

#define LDK 136   // padded LDS leading dim (qkv/final): 4-bank shift per row
#define TIDX(r, c) ((r) * LDK + ((c) ^ (((r) & 3) << 5)))
// attn: 32KB linear tile, 16B-chunk XOR swizzle (r4-proven). Linear rows ->
// global_load_lds-compatible (swizzle applied on the SOURCE address, rule #21).
#define TIDX8(r, c) ((r) * 128 + ((c) ^ (((r) & 7) << 3)))
#define MFMA(a, b, c) __builtin_amdgcn_mfma_f32_16x16x32_bf16(a, b, c, 0, 0, 0)

__device__ __forceinline__ u16 f2b(float f) {
  u32 u = __builtin_bit_cast(u32, f);
  u = (u + 0x7fffu + ((u >> 16) & 1u)) >> 16;
  return (u16)u;
}
__device__ __forceinline__ float b2f(u16 h) {
  u32 u = ((u32)h) << 16;
  return __builtin_bit_cast(float, u);
}
__device__ __forceinline__ u32 pk2(float lo, float hi) {
  return (u32)f2b(lo) | ((u32)f2b(hi) << 16);
}
// async global->LDS 16B: per-lane global src, wave-uniform LDS base + lane*16
__device__ __forceinline__ void gl2lds16(const u16* g, u16* l) {
  __builtin_amdgcn_global_load_lds(
      (const __attribute__((address_space(1))) unsigned int*)g,
      (__attribute__((address_space(3))) unsigned int*)l, 16, 0, 0);
}

// ---------------- weight prep: wT[m][d][c] = bf16(W_m[c][d]) ----------------
__global__ void wprep(const float* __restrict__ Wq, const float* __restrict__ Wk,
                      const float* __restrict__ Wv, const float* __restrict__ Ws,
                      u16* __restrict__ wT) {
  const float* srcs[4] = {Wq, Wk, Wv, Ws};
  const float* s = srcs[blockIdx.x];
  u16* d = wT + (size_t)blockIdx.x * 16384;
  for (int idx = threadIdx.x; idx < 16384; idx += 256) {
    int i = idx >> 7, j = idx & 127;   // W[i=c_in][j=c_out]
    d[j * 128 + i] = f2b(s[idx]);
  }
}

// ---------------- QKV: GEMM + ReLU + LDS-bounce coalesced store (r7 proven) --------
__global__ __launch_bounds__(256, 4)
void qkv_kernel(const float* __restrict__ x1, const float* __restrict__ x2,
                const u16* __restrict__ wT,
                u16* __restrict__ q_t, u16* __restrict__ k_t, u16* __restrict__ v_t) {
  __shared__ u16 Xs[128 * LDK];   // x tile [w][c] bf16; later bounce tile [c][w]

  const int t = threadIdx.x;
  const int bid = blockIdx.x;
  const int xs = bid & 7;
  const int m = (bid >> 3) % 3;            // 0=q, 1=k, 2=v
  const int bh = (bid / 24) * 8 + xs;      // each (bh,m) exactly once; XCD-grouped
  const int b = bh >> 7, h = bh & 127;
  const size_t pixbase = (size_t)bh * 16384;
  const size_t obase = (size_t)b * 2097152 + (size_t)h * 128;

  const float* xin = (m == 2) ? x2 : x1;
  u16* dst = (m == 0) ? q_t : (m == 1) ? k_t : v_t;

  const int lane = t & 63, wave = t >> 6;
  const int lrow = lane & 15, lq = lane >> 4;
  const int nstrip = wave * 32;

  // stage x row-tile -> Xs[w][c] bf16 (swizzled); loads issued first
#pragma unroll
  for (int j = 0; j < 8; ++j) {
    int lin = j * 256 + t;
    int w = lin >> 4, c0 = (lin & 15) << 3;
    f32x4 a0 = *(const f32x4*)&xin[pixbase + lin * 8];
    f32x4 a1 = *(const f32x4*)&xin[pixbase + lin * 8 + 4];
    u16x8 p;
#pragma unroll
    for (int i = 0; i < 4; ++i) { p[i] = f2b(a0[i]); p[4 + i] = f2b(a1[i]); }
    *(u16x8*)&Xs[TIDX(w, c0)] = p;
  }

  // B fragments straight from global (L2-hot)
  const u16* wb = wT + (size_t)m * 16384;
  bf16x8 w0[4], w1[4];
#pragma unroll
  for (int kk = 0; kk < 4; ++kk) {
    int ko = kk * 32 + lq * 8;
    w0[kk] = *(const bf16x8*)&wb[(nstrip + lrow) * 128 + ko];
    w1[kk] = *(const bf16x8*)&wb[(nstrip + 16 + lrow) * 128 + ko];
  }
  __syncthreads();

  f32x4 acc[8][2];
#pragma unroll
  for (int mt = 0; mt < 8; ++mt) {
    acc[mt][0] = (f32x4){0.f, 0.f, 0.f, 0.f};
    acc[mt][1] = (f32x4){0.f, 0.f, 0.f, 0.f};
  }
#pragma unroll
  for (int kk = 0; kk < 4; ++kk) {
    int ko = kk * 32 + lq * 8;
#pragma unroll
    for (int mt = 0; mt < 8; ++mt) {
      bf16x8 a = *(const bf16x8*)&Xs[TIDX(mt * 16 + lrow, ko)];
      acc[mt][0] = MFMA(a, w0[kk], acc[mt][0]);
      acc[mt][1] = MFMA(a, w1[kk], acc[mt][1]);
    }
  }
  __syncthreads();   // all GEMM reads of Xs done -> reuse as bounce tile

  // bounce: relu(acc) -> Xs[c][w]
#pragma unroll
  for (int mt = 0; mt < 8; ++mt) {
    int w0i = mt * 16 + lq * 4;
#pragma unroll
    for (int nt = 0; nt < 2; ++nt) {
      int c = nstrip + nt * 16 + lrow;
      u32x2 p;
      p[0] = pk2(fmaxf(acc[mt][nt][0], 0.f), fmaxf(acc[mt][nt][1], 0.f));
      p[1] = pk2(fmaxf(acc[mt][nt][2], 0.f), fmaxf(acc[mt][nt][3], 0.f));
      *(u32x2*)&Xs[TIDX(c, w0i)] = p;
    }
  }
  __syncthreads();

  // coalesced store: per j, 16 full c-rows (256B contiguous each)
#pragma unroll
  for (int j = 0; j < 8; ++j) {
    int c = j * 16 + (t >> 4), wv = (t & 15) * 8;
    *(u16x8*)&dst[obase + (size_t)c * 16384 + wv] = *(const u16x8*)&Xs[TIDX(c, wv)];
  }
}

// ---------------- attention: per (b,c); S^T = K Q^T, softmax over g, O^T = V^T P^T --
// 32KB linear Ks (K via global_load_lds with pre-swizzled source -> V^T -> O bounce).
// P in registers (packed bf16), redistributed to PV B-fragments via shfl (r4-verified).
__global__ __launch_bounds__(256, 4)
void attn_kernel(u16* __restrict__ q_t, const u16* __restrict__ k_t,
                 const u16* __restrict__ v_t, const float* __restrict__ scale_p) {
  __shared__ u16 Ks[128 * 128];

  const int t = threadIdx.x;
  const size_t base = (size_t)blockIdx.x * 16384;

  const int lane = t & 63, wave = t >> 6;
  const int lrow = lane & 15, lq = lane >> 4;
  const int hstrip = wave * 32;
  const float scl = scale_p[0];

  // K stage: async DMA, linear LDS dest; swizzle folded into the SOURCE address
  // so TIDX8 reads find K[r][c]. Lane handles chunk lin=j*256+t.
#pragma unroll
  for (int j = 0; j < 8; ++j) {
    int lin = j * 256 + t;
    int r = lin >> 4, c0 = (lin & 15) << 3;
    int csw = c0 ^ ((r & 7) << 3);
    gl2lds16(&k_t[base + r * 128 + csw], &Ks[(size_t)(j * 256 + (t & 192)) * 8]);
  }

  // Q fragments (per-wave-private rows) straight from global
  bf16x8 q0[4], q1[4];
#pragma unroll
  for (int kk = 0; kk < 4; ++kk) {
    int ko = kk * 32 + lq * 8;
    q0[kk] = *(const bf16x8*)&q_t[base + (hstrip + lrow) * 128 + ko];
    q1[kk] = *(const bf16x8*)&q_t[base + (hstrip + 16 + lrow) * 128 + ko];
  }
  __syncthreads();   // drains gload_lds (compiler emits vmcnt(0) before barrier)

  // S^T[g][h]: A = Ks rows g, B = Q frags
  f32x4 acc[8][2];
#pragma unroll
  for (int mt = 0; mt < 8; ++mt) {
    acc[mt][0] = (f32x4){0.f, 0.f, 0.f, 0.f};
    acc[mt][1] = (f32x4){0.f, 0.f, 0.f, 0.f};
  }
#pragma unroll
  for (int kk = 0; kk < 4; ++kk) {
    int ko = kk * 32 + lq * 8;
#pragma unroll
    for (int mt = 0; mt < 8; ++mt) {
      bf16x8 a = *(const bf16x8*)&Ks[TIDX8(mt * 16 + lrow, ko)];
      acc[mt][0] = MFMA(a, q0[kk], acc[mt][0]);
      acc[mt][1] = MFMA(a, q1[kk], acc[mt][1]);
    }
  }

  // V loads issued now (coalesced 256B runs); latency hides under softmax+pack
  const int w0v = (t & 15) * 8, g0 = (t >> 4) * 8;
  u16x8 vv[8];
#pragma unroll
  for (int i = 0; i < 8; ++i)
    vv[i] = *(const u16x8*)&v_t[base + (size_t)(g0 + i) * 128 + w0v];

  // softmax over g: per-lane 32 values + quad combine via shfl_xor 16/32
  float inv[2];
#pragma unroll
  for (int nt = 0; nt < 2; ++nt) {
    float mx = -1e30f;
#pragma unroll
    for (int mt = 0; mt < 8; ++mt)
#pragma unroll
      for (int r = 0; r < 4; ++r) {
        acc[mt][nt][r] *= scl;
        mx = fmaxf(mx, acc[mt][nt][r]);
      }
    mx = fmaxf(mx, __shfl_xor(mx, 16));
    mx = fmaxf(mx, __shfl_xor(mx, 32));
    float s = 0.f;
#pragma unroll
    for (int mt = 0; mt < 8; ++mt)
#pragma unroll
      for (int r = 0; r < 4; ++r) {
        float e = __expf(acc[mt][nt][r] - mx);
        acc[mt][nt][r] = e;
        s += e;
      }
    s += __shfl_xor(s, 16);
    s += __shfl_xor(s, 32);
    inv[nt] = 1.f / s;
  }

  // pack P (with 1/sum folded) into registers: pk[mt][nt][pair]
  u32 pk[8][2][2];
#pragma unroll
  for (int mt = 0; mt < 8; ++mt)
#pragma unroll
    for (int nt = 0; nt < 2; ++nt) {
      pk[mt][nt][0] = pk2(acc[mt][nt][0] * inv[nt], acc[mt][nt][1] * inv[nt]);
      pk[mt][nt][1] = pk2(acc[mt][nt][2] * inv[nt], acc[mt][nt][3] * inv[nt]);
    }
  __syncthreads();   // all S-MFMA reads of Ks complete -> K dead

  // V^T into Ks (register 8x8 transpose, static indexing only)
#pragma unroll
  for (int j = 0; j < 8; ++j) {
    u16x8 tv;
#pragma unroll
    for (int i = 0; i < 8; ++i) tv[i] = vv[i][j];
    *(u16x8*)&Ks[TIDX8(w0v + j, g0)] = tv;
  }
  __syncthreads();

  // O^T[w][h]: A = Ks(V^T) rows w, B = P from registers via shfl redistribution
  const int s01 = lrow + 32 * (lq & 1);
  const int s23 = s01 + 16;
  const bool hi = (lq & 2);
#pragma unroll
  for (int kk = 0; kk < 4; ++kk) {
    int ko = kk * 32 + lq * 8;
    u32x4 bd[2];
#pragma unroll
    for (int nt = 0; nt < 2; ++nt) {
      u32 a0 = pk[2 * kk][nt][0], a1 = pk[2 * kk][nt][1];
      u32 c0 = pk[2 * kk + 1][nt][0], c1 = pk[2 * kk + 1][nt][1];
      u32 l0 = (u32)__shfl((int)a0, s01), h0 = (u32)__shfl((int)c0, s01);
      u32 l1 = (u32)__shfl((int)a1, s01), h1 = (u32)__shfl((int)c1, s01);
      u32 l2 = (u32)__shfl((int)a0, s23), h2 = (u32)__shfl((int)c0, s23);
      u32 l3 = (u32)__shfl((int)a1, s23), h3 = (u32)__shfl((int)c1, s23);
      bd[nt][0] = hi ? h0 : l0;
      bd[nt][1] = hi ? h1 : l1;
      bd[nt][2] = hi ? h2 : l2;
      bd[nt][3] = hi ? h3 : l3;
    }
    bf16x8 bb0 = __builtin_bit_cast(bf16x8, bd[0]);
    bf16x8 bb1 = __builtin_bit_cast(bf16x8, bd[1]);
    if (kk == 0) {
#pragma unroll
      for (int mt = 0; mt < 8; ++mt) {
        acc[mt][0] = (f32x4){0.f, 0.f, 0.f, 0.f};
        acc[mt][1] = (f32x4){0.f, 0.f, 0.f, 0.f};
      }
    }
#pragma unroll
    for (int mt = 0; mt < 8; ++mt) {
      bf16x8 a = *(const bf16x8*)&Ks[TIDX8(mt * 16 + lrow, ko)];
      acc[mt][0] = MFMA(a, bb0, acc[mt][0]);
      acc[mt][1] = MFMA(a, bb1, acc[mt][1]);
    }
  }
  __syncthreads();   // PV reads of Ks done -> reuse as O bounce tile

  // bounce O -> Ks[h][w], then fully-contiguous store
#pragma unroll
  for (int mt = 0; mt < 8; ++mt) {
    int w0i = mt * 16 + lq * 4;
#pragma unroll
    for (int nt = 0; nt < 2; ++nt) {
      int hh = hstrip + nt * 16 + lrow;
      u32x2 p;
      p[0] = pk2(acc[mt][nt][0], acc[mt][nt][1]);
      p[1] = pk2(acc[mt][nt][2], acc[mt][nt][3]);
      *(u32x2*)&Ks[TIDX8(hh, w0i)] = p;
    }
  }
  __syncthreads();
#pragma unroll
  for (int j = 0; j < 8; ++j) {
    int hh = j * 16 + (t >> 4), wv = (t & 15) * 8;
    *(u16x8*)&q_t[base + hh * 128 + wv] = *(const u16x8*)&Ks[TIDX8(hh, wv)];
  }
}

// ---------------- final: s = o @ Ws + bs; sigmoid; BN; out = x1 + x2*g (r7 proven) --
__global__ __launch_bounds__(256, 4)
void final_kernel(const u16* __restrict__ o_t, const u16* __restrict__ wsT,
                  const float* __restrict__ x1, const float* __restrict__ x2,
                  const float* __restrict__ bs, const float* __restrict__ gamma,
                  const float* __restrict__ beta, const float* __restrict__ mu,
                  const float* __restrict__ var, float* __restrict__ out) {
  __shared__ u16 Os[128 * LDK];   // o^T tile [w][c] (swizzled)
  __shared__ float bnA[128], bnB[128], bsf[128];

  const int t = threadIdx.x;
  const int bh = blockIdx.x;
  const int b = bh >> 7, h = bh & 127;
  const size_t obase = (size_t)b * 2097152 + (size_t)h * 128;
  const size_t pixbase = (size_t)bh * 16384;

  if (t < 128) {
    float a = gamma[t] * rsqrtf(var[t] + 1e-3f);
    bnA[t] = a;
    bnB[t] = beta[t] - mu[t] * a;
    bsf[t] = bs[t];
  }
  {  // coalesced transpose-load o tile -> Os[w][c] (static indexing only)
    int cb = (t >> 4) * 8, w0 = (t & 15) * 8;
    u16 ov[8][8];
#pragma unroll
    for (int i = 0; i < 8; ++i)
      *(u16x8*)&ov[i][0] = *(const u16x8*)&o_t[obase + (size_t)(cb + i) * 16384 + w0];
#pragma unroll
    for (int j = 0; j < 8; ++j) {
      u16x8 tv;
#pragma unroll
      for (int i = 0; i < 8; ++i) tv[i] = ov[i][j];
      *(u16x8*)&Os[TIDX(w0 + j, cb)] = tv;
    }
  }
  __syncthreads();

  const int lane = t & 63, wave = t >> 6;
  const int lrow = lane & 15, lq = lane >> 4;
  const int wstrip = wave * 32;

  // D[d][w] = sum_c WsT[d][c] * Os[w][c]; A fragments straight from global (L2-hot)
  f32x4 acc[8][2];
#pragma unroll
  for (int mt = 0; mt < 8; ++mt) {
    acc[mt][0] = (f32x4){0.f, 0.f, 0.f, 0.f};
    acc[mt][1] = (f32x4){0.f, 0.f, 0.f, 0.f};
  }
#pragma unroll
  for (int kk = 0; kk < 4; ++kk) {
    int ko = kk * 32 + lq * 8;
    bf16x8 b0 = *(const bf16x8*)&Os[TIDX(wstrip + lrow, ko)];
    bf16x8 b1 = *(const bf16x8*)&Os[TIDX(wstrip + 16 + lrow, ko)];
#pragma unroll
    for (int mt = 0; mt < 8; ++mt) {
      bf16x8 a = *(const bf16x8*)&wsT[(mt * 16 + lrow) * 128 + ko];
      acc[mt][0] = MFMA(a, b0, acc[mt][0]);
      acc[mt][1] = MFMA(a, b1, acc[mt][1]);
    }
  }

  // fused epilogue: sigmoid + BN + gated residual, direct coalesced f32x4 I/O
#pragma unroll
  for (int mt = 0; mt < 8; ++mt) {
    int d0 = mt * 16 + lq * 4;
    f32x4 A4 = *(const f32x4*)&bnA[d0];
    f32x4 B4 = *(const f32x4*)&bnB[d0];
    f32x4 S4 = *(const f32x4*)&bsf[d0];
#pragma unroll
    for (int nt = 0; nt < 2; ++nt) {
      int w = wstrip + nt * 16 + lrow;
      size_t off = pixbase + (size_t)w * 128 + d0;
      f32x4 a1v = *(const f32x4*)&x1[off];
      f32x4 a2v = *(const f32x4*)&x2[off];
      f32x4 r;
#pragma unroll
      for (int r4 = 0; r4 < 4; ++r4) {
        float sv = acc[mt][nt][r4] + S4[r4];
        float sg = 1.f / (1.f + __expf(-sv));
        float g = A4[r4] * sg + B4[r4];
        r[r4] = a1v[r4] + a2v[r4] * g;
      }
      *(f32x4*)&out[off] = r;
    }
  }
}

extern "C" void kernel_launch(void* const* d_in, const int* in_sizes, int n_in,
                              void* d_out, int out_size, void* d_ws, size_t ws_size,
                              hipStream_t stream) {
  const float* x1 = (const float*)d_in[0];
  const float* x2 = (const float*)d_in[1];
  const float* Wq = (const float*)d_in[2];
  const float* Wk = (const float*)d_in[3];
  const float* Wv = (const float*)d_in[4];
  const float* Ws = (const float*)d_in[5];
  const float* bs = (const float*)d_in[6];
  const float* scale = (const float*)d_in[7];
  const float* gamma = (const float*)d_in[8];
  const float* beta = (const float*)d_in[9];
  const float* mu = (const float*)d_in[10];
  const float* var = (const float*)d_in[11];
  float* outp = (float*)d_out;

  // workspace (bf16 elems): q_t | k_t | v_t : [B][C][H][W], then 4 transposed weights
  u16* q_t = (u16*)d_ws;
  u16* k_t = q_t + 16777216;
  u16* v_t = k_t + 16777216;
  u16* wT = v_t + 16777216;  // 4 * 16384

  wprep<<<dim3(4), dim3(256), 0, stream>>>(Wq, Wk, Wv, Ws, wT);
  qkv_kernel<<<dim3(3072), dim3(256), 0, stream>>>(x1, x2, wT, q_t, k_t, v_t);
  attn_kernel<<<dim3(1024), dim3(256), 0, stream>>>(q_t, k_t, v_t, scale);
  final_kernel<<<dim3(1024), dim3(256), 0, stream>>>(q_t, wT + 3 * 16384, x1, x2, bs,
                                                     gamma, beta, mu, var, outp);
}

// Round 11
// 315.997 us; speedup vs baseline: 1.1032x; 1.0276x over previous
//
#include <hip/hip_runtime.h>

typedef unsigned int u32;
typedef unsigned short u16;
typedef unsigned char u8;
typedef u16 u16x4 __attribute__((ext_vector_type(4)));
typedef u16 u16x8 __attribute__((ext_vector_type(8)));
typedef u32 u32x2 __attribute__((ext_vector_type(2)));
typedef u32 u32x4 __attribute__((ext_vector_type(4)));
typedef __bf16 bf16x8 __attribute__((ext_vector_type(8)));
typedef float f32x2 __attribute__((ext_vector_type(2)));
typedef float f32x4 __attribute__((ext_vector_type(4)));
typedef long long i64;

#define LDK 136   // padded LDS leading dim (qkv stage / final): 4-bank shift per row
#define TIDX(r, c) ((r) * LDK + ((c) ^ (((r) & 3) << 5)))
// attn V^T/O phase: 32KB linear u16 tile, 16B-chunk XOR swizzle (r4-proven)
#define TIDX8(r, c) ((r) * 128 + ((c) ^ (((r) & 7) << 3)))
#define MFMA(a, b, c) __builtin_amdgcn_mfma_f32_16x16x32_bf16(a, b, c, 0, 0, 0)
#define MFMA8(a, b, c) __builtin_amdgcn_mfma_f32_16x16x32_fp8_fp8(a, b, c, 0, 0, 0)

__device__ __forceinline__ u16 f2b(float f) {
  u32 u = __builtin_bit_cast(u32, f);
  u = (u + 0x7fffu + ((u >> 16) & 1u)) >> 16;
  return (u16)u;
}
__device__ __forceinline__ u32 pk2(float lo, float hi) {
  return (u32)f2b(lo) | ((u32)f2b(hi) << 16);
}
// 4 floats -> 4 fp8 e4m3 bytes (w order preserved)
__device__ __forceinline__ u32 pk4f8(float a, float b, float c, float d) {
  int v = __builtin_amdgcn_cvt_pk_fp8_f32(a, b, 0, false);
  v = __builtin_amdgcn_cvt_pk_fp8_f32(c, d, v, true);
  return (u32)v;
}
// async global->LDS 16B: per-lane global src, wave-uniform LDS base + lane*16
__device__ __forceinline__ void gl2lds16(const void* g, void* l) {
  __builtin_amdgcn_global_load_lds(
      (const __attribute__((address_space(1))) unsigned int*)g,
      (__attribute__((address_space(3))) unsigned int*)l, 16, 0, 0);
}

// ---------------- weight prep: wT[m][d][c] = bf16(W_m[c][d]) ----------------
__global__ void wprep(const float* __restrict__ Wq, const float* __restrict__ Wk,
                      const float* __restrict__ Wv, const float* __restrict__ Ws,
                      u16* __restrict__ wT) {
  const float* srcs[4] = {Wq, Wk, Wv, Ws};
  const float* s = srcs[blockIdx.x];
  u16* d = wT + (size_t)blockIdx.x * 16384;
  for (int idx = threadIdx.x; idx < 16384; idx += 256) {
    int i = idx >> 7, j = idx & 127;   // W[i=c_in][j=c_out]
    d[j * 128 + i] = f2b(s[idx]);
  }
}

// ---------------- QKV: bf16 GEMM (r7-proven) + fp8 output pack ----------------
// Bounce tile: u8[c][w], pitch 144B (16B-aligned rows, 4-dword bank rotation).
// Store: per j, 8 c-rows x 128B full lines per wave instr.
__global__ __launch_bounds__(256, 4)
void qkv_kernel(const float* __restrict__ x1, const float* __restrict__ x2,
                const u16* __restrict__ wT,
                u8* __restrict__ q8, u8* __restrict__ k8, u8* __restrict__ v8) {
  __shared__ u16 Xs[128 * LDK];   // stage [w][c] bf16; later u8 bounce tile (18KB)

  const int t = threadIdx.x;
  const int bid = blockIdx.x;
  const int xs = bid & 7;
  const int m = (bid >> 3) % 3;            // 0=q, 1=k, 2=v
  const int bh = (bid / 24) * 8 + xs;      // each (bh,m) exactly once; XCD-grouped
  const int b = bh >> 7, h = bh & 127;
  const size_t pixbase = (size_t)bh * 16384;
  const size_t obase8 = (size_t)b * 2097152 + (size_t)h * 128;   // bytes

  const float* xin = (m == 2) ? x2 : x1;
  u8* dst = (m == 0) ? q8 : (m == 1) ? k8 : v8;

  const int lane = t & 63, wave = t >> 6;
  const int lrow = lane & 15, lq = lane >> 4;
  const int nstrip = wave * 32;

  // stage x row-tile -> Xs[w][c] bf16 (swizzled)
#pragma unroll
  for (int j = 0; j < 8; ++j) {
    int lin = j * 256 + t;
    int w = lin >> 4, c0 = (lin & 15) << 3;
    f32x4 a0 = *(const f32x4*)&xin[pixbase + lin * 8];
    f32x4 a1 = *(const f32x4*)&xin[pixbase + lin * 8 + 4];
    u16x8 p;
#pragma unroll
    for (int i = 0; i < 4; ++i) { p[i] = f2b(a0[i]); p[4 + i] = f2b(a1[i]); }
    *(u16x8*)&Xs[TIDX(w, c0)] = p;
  }

  // B fragments straight from global (L2-hot)
  const u16* wb = wT + (size_t)m * 16384;
  bf16x8 w0[4], w1[4];
#pragma unroll
  for (int kk = 0; kk < 4; ++kk) {
    int ko = kk * 32 + lq * 8;
    w0[kk] = *(const bf16x8*)&wb[(nstrip + lrow) * 128 + ko];
    w1[kk] = *(const bf16x8*)&wb[(nstrip + 16 + lrow) * 128 + ko];
  }
  __syncthreads();

  f32x4 acc[8][2];
#pragma unroll
  for (int mt = 0; mt < 8; ++mt) {
    acc[mt][0] = (f32x4){0.f, 0.f, 0.f, 0.f};
    acc[mt][1] = (f32x4){0.f, 0.f, 0.f, 0.f};
  }
#pragma unroll
  for (int kk = 0; kk < 4; ++kk) {
    int ko = kk * 32 + lq * 8;
#pragma unroll
    for (int mt = 0; mt < 8; ++mt) {
      bf16x8 a = *(const bf16x8*)&Xs[TIDX(mt * 16 + lrow, ko)];
      acc[mt][0] = MFMA(a, w0[kk], acc[mt][0]);
      acc[mt][1] = MFMA(a, w1[kk], acc[mt][1]);
    }
  }
  __syncthreads();   // all GEMM reads of Xs done -> reuse as u8 bounce tile

  // bounce: relu(acc) -> fp8 -> Xs8[c][w] (pitch 144B)
  u8* Xs8 = (u8*)Xs;
#pragma unroll
  for (int mt = 0; mt < 8; ++mt) {
    int w0i = mt * 16 + lq * 4;   // byte offset (1B/elem)
#pragma unroll
    for (int nt = 0; nt < 2; ++nt) {
      int c = nstrip + nt * 16 + lrow;
      u32 p = pk4f8(fmaxf(acc[mt][nt][0], 0.f), fmaxf(acc[mt][nt][1], 0.f),
                    fmaxf(acc[mt][nt][2], 0.f), fmaxf(acc[mt][nt][3], 0.f));
      *(u32*)&Xs8[c * 144 + w0i] = p;
    }
  }
  __syncthreads();

  // coalesced store: per j, 8 c-rows x 128B (full lines)
#pragma unroll
  for (int j = 0; j < 4; ++j) {
    int c = j * 32 + (t >> 3), bo = (t & 7) * 16;
    u32x4 v = *(const u32x4*)&Xs8[c * 144 + bo];
    *(u32x4*)&dst[obase8 + (size_t)c * 16384 + bo] = v;
  }
}

// ---------------- attention: fp8 QK^T, bf16 softmax/PV; O -> o_t (bf16) ------------
// K staged fp8 (16KB, DMA + source swizzle); V expanded fp8->bf16 in-register;
// P-in-regs shfl redistribution unchanged (r4-verified).
__global__ __launch_bounds__(256, 4)
void attn_kernel(const u8* __restrict__ q8, const u8* __restrict__ k8,
                 const u8* __restrict__ v8, u16* __restrict__ o16,
                 const float* __restrict__ scale_p) {
  __shared__ u16 Ks[128 * 128];   // K phase: low 16KB as u8; later V^T/O bf16 tile
  u8* Ks8 = (u8*)Ks;

  const int t = threadIdx.x;
  const size_t base8 = (size_t)blockIdx.x * 16384;    // bytes (fp8 plane)
  const size_t base16 = (size_t)blockIdx.x * 16384;   // u16 elems (o plane)

  const int lane = t & 63, wave = t >> 6;
  const int lrow = lane & 15, lq = lane >> 4;
  const int hstrip = wave * 32;
  const float scl = scale_p[0];
  const int swl = (lrow & 7) << 4;   // per-lane K source/read swizzle

  // K stage: async DMA, linear LDS dest; swizzle folded into SOURCE address
#pragma unroll
  for (int j = 0; j < 4; ++j) {
    int lin = j * 256 + t;
    int r = lin >> 3, c16 = (lin & 7) << 4;
    gl2lds16(&k8[base8 + r * 128 + (c16 ^ ((r & 7) << 4))],
             &Ks8[(size_t)(j * 256 + (t & 192)) * 16]);
  }

  // Q fragments (fp8, 8B each) straight from global
  i64 q0[4], q1[4];
#pragma unroll
  for (int kk = 0; kk < 4; ++kk) {
    int ko = kk * 32 + lq * 8;
    q0[kk] = *(const i64*)&q8[base8 + (hstrip + lrow) * 128 + ko];
    q1[kk] = *(const i64*)&q8[base8 + (hstrip + 16 + lrow) * 128 + ko];
  }
  __syncthreads();   // drains gload_lds

  // S^T[g][h]: A = K fp8 rows g, B = Q fp8 frags
  f32x4 acc[8][2];
#pragma unroll
  for (int mt = 0; mt < 8; ++mt) {
    acc[mt][0] = (f32x4){0.f, 0.f, 0.f, 0.f};
    acc[mt][1] = (f32x4){0.f, 0.f, 0.f, 0.f};
  }
#pragma unroll
  for (int kk = 0; kk < 4; ++kk) {
    int ko = kk * 32 + lq * 8;
#pragma unroll
    for (int mt = 0; mt < 8; ++mt) {
      i64 a = *(const i64*)&Ks8[(mt * 16 + lrow) * 128 + (ko ^ swl)];
      acc[mt][0] = MFMA8(a, q0[kk], acc[mt][0]);
      acc[mt][1] = MFMA8(a, q1[kk], acc[mt][1]);
    }
  }

  // V loads (fp8, coalesced 128B runs); latency hides under softmax+pack
  const int w0v = (t & 15) * 8, g0 = (t >> 4) * 8;
  u32x2 vv[8];
#pragma unroll
  for (int i = 0; i < 8; ++i)
    vv[i] = *(const u32x2*)&v8[base8 + (size_t)(g0 + i) * 128 + w0v];

  // softmax over g: per-lane 32 values + quad combine via shfl_xor 16/32
  float inv[2];
#pragma unroll
  for (int nt = 0; nt < 2; ++nt) {
    float mx = -1e30f;
#pragma unroll
    for (int mt = 0; mt < 8; ++mt)
#pragma unroll
      for (int r = 0; r < 4; ++r) {
        acc[mt][nt][r] *= scl;
        mx = fmaxf(mx, acc[mt][nt][r]);
      }
    mx = fmaxf(mx, __shfl_xor(mx, 16));
    mx = fmaxf(mx, __shfl_xor(mx, 32));
    float s = 0.f;
#pragma unroll
    for (int mt = 0; mt < 8; ++mt)
#pragma unroll
      for (int r = 0; r < 4; ++r) {
        float e = __expf(acc[mt][nt][r] - mx);
        acc[mt][nt][r] = e;
        s += e;
      }
    s += __shfl_xor(s, 16);
    s += __shfl_xor(s, 32);
    inv[nt] = 1.f / s;
  }

  // pack P (with 1/sum folded) into registers: pk[mt][nt][pair] (bf16 pairs)
  u32 pk[8][2][2];
#pragma unroll
  for (int mt = 0; mt < 8; ++mt)
#pragma unroll
    for (int nt = 0; nt < 2; ++nt) {
      pk[mt][nt][0] = pk2(acc[mt][nt][0] * inv[nt], acc[mt][nt][1] * inv[nt]);
      pk[mt][nt][1] = pk2(acc[mt][nt][2] * inv[nt], acc[mt][nt][3] * inv[nt]);
    }
  __syncthreads();   // all S-MFMA reads of K complete -> K dead

  // V expand fp8->bf16 (per row), then 8x8 transpose into Ks[TIDX8] (static idx)
  u16x8 bb[8];
#pragma unroll
  for (int i = 0; i < 8; ++i) {
    f32x2 p0 = __builtin_amdgcn_cvt_pk_f32_fp8((int)vv[i][0], false);
    f32x2 p1 = __builtin_amdgcn_cvt_pk_f32_fp8((int)vv[i][0], true);
    f32x2 p2 = __builtin_amdgcn_cvt_pk_f32_fp8((int)vv[i][1], false);
    f32x2 p3 = __builtin_amdgcn_cvt_pk_f32_fp8((int)vv[i][1], true);
    bb[i][0] = f2b(p0[0]); bb[i][1] = f2b(p0[1]);
    bb[i][2] = f2b(p1[0]); bb[i][3] = f2b(p1[1]);
    bb[i][4] = f2b(p2[0]); bb[i][5] = f2b(p2[1]);
    bb[i][6] = f2b(p3[0]); bb[i][7] = f2b(p3[1]);
  }
#pragma unroll
  for (int j = 0; j < 8; ++j) {
    u16x8 tv;
#pragma unroll
    for (int i = 0; i < 8; ++i) tv[i] = bb[i][j];
    *(u16x8*)&Ks[TIDX8(w0v + j, g0)] = tv;
  }
  __syncthreads();

  // O^T[w][h]: A = Ks(V^T bf16) rows w, B = P via shfl redistribution
  const int s01 = lrow + 32 * (lq & 1);
  const int s23 = s01 + 16;
  const bool hi = (lq & 2);
#pragma unroll
  for (int kk = 0; kk < 4; ++kk) {
    int ko = kk * 32 + lq * 8;
    u32x4 bd[2];
#pragma unroll
    for (int nt = 0; nt < 2; ++nt) {
      u32 a0 = pk[2 * kk][nt][0], a1 = pk[2 * kk][nt][1];
      u32 c0 = pk[2 * kk + 1][nt][0], c1 = pk[2 * kk + 1][nt][1];
      u32 l0 = (u32)__shfl((int)a0, s01), h0 = (u32)__shfl((int)c0, s01);
      u32 l1 = (u32)__shfl((int)a1, s01), h1 = (u32)__shfl((int)c1, s01);
      u32 l2 = (u32)__shfl((int)a0, s23), h2 = (u32)__shfl((int)c0, s23);
      u32 l3 = (u32)__shfl((int)a1, s23), h3 = (u32)__shfl((int)c1, s23);
      bd[nt][0] = hi ? h0 : l0;
      bd[nt][1] = hi ? h1 : l1;
      bd[nt][2] = hi ? h2 : l2;
      bd[nt][3] = hi ? h3 : l3;
    }
    bf16x8 bb0 = __builtin_bit_cast(bf16x8, bd[0]);
    bf16x8 bb1 = __builtin_bit_cast(bf16x8, bd[1]);
    if (kk == 0) {
#pragma unroll
      for (int mt = 0; mt < 8; ++mt) {
        acc[mt][0] = (f32x4){0.f, 0.f, 0.f, 0.f};
        acc[mt][1] = (f32x4){0.f, 0.f, 0.f, 0.f};
      }
    }
#pragma unroll
    for (int mt = 0; mt < 8; ++mt) {
      bf16x8 a = *(const bf16x8*)&Ks[TIDX8(mt * 16 + lrow, ko)];
      acc[mt][0] = MFMA(a, bb0, acc[mt][0]);
      acc[mt][1] = MFMA(a, bb1, acc[mt][1]);
    }
  }
  __syncthreads();   // PV reads of Ks done -> reuse as O bounce tile

  // bounce O -> Ks[h][w] (bf16), then fully-contiguous store to o_t
#pragma unroll
  for (int mt = 0; mt < 8; ++mt) {
    int w0i = mt * 16 + lq * 4;
#pragma unroll
    for (int nt = 0; nt < 2; ++nt) {
      int hh = hstrip + nt * 16 + lrow;
      u32x2 p;
      p[0] = pk2(acc[mt][nt][0], acc[mt][nt][1]);
      p[1] = pk2(acc[mt][nt][2], acc[mt][nt][3]);
      *(u32x2*)&Ks[TIDX8(hh, w0i)] = p;
    }
  }
  __syncthreads();
#pragma unroll
  for (int j = 0; j < 8; ++j) {
    int hh = j * 16 + (t >> 4), wv = (t & 15) * 8;
    *(u16x8*)&o16[base16 + hh * 128 + wv] = *(const u16x8*)&Ks[TIDX8(hh, wv)];
  }
}

// ---------------- final: s = o @ Ws + bs; sigmoid; BN; out = x1 + x2*g (r7 proven) --
__global__ __launch_bounds__(256, 4)
void final_kernel(const u16* __restrict__ o_t, const u16* __restrict__ wsT,
                  const float* __restrict__ x1, const float* __restrict__ x2,
                  const float* __restrict__ bs, const float* __restrict__ gamma,
                  const float* __restrict__ beta, const float* __restrict__ mu,
                  const float* __restrict__ var, float* __restrict__ out) {
  __shared__ u16 Os[128 * LDK];   // o^T tile [w][c] (swizzled)
  __shared__ float bnA[128], bnB[128], bsf[128];

  const int t = threadIdx.x;
  const int bh = blockIdx.x;
  const int b = bh >> 7, h = bh & 127;
  const size_t obase = (size_t)b * 2097152 + (size_t)h * 128;
  const size_t pixbase = (size_t)bh * 16384;

  if (t < 128) {
    float a = gamma[t] * rsqrtf(var[t] + 1e-3f);
    bnA[t] = a;
    bnB[t] = beta[t] - mu[t] * a;
    bsf[t] = bs[t];
  }
  {  // coalesced transpose-load o tile -> Os[w][c] (static indexing only)
    int cb = (t >> 4) * 8, w0 = (t & 15) * 8;
    u16 ov[8][8];
#pragma unroll
    for (int i = 0; i < 8; ++i)
      *(u16x8*)&ov[i][0] = *(const u16x8*)&o_t[obase + (size_t)(cb + i) * 16384 + w0];
#pragma unroll
    for (int j = 0; j < 8; ++j) {
      u16x8 tv;
#pragma unroll
      for (int i = 0; i < 8; ++i) tv[i] = ov[i][j];
      *(u16x8*)&Os[TIDX(w0 + j, cb)] = tv;
    }
  }
  __syncthreads();

  const int lane = t & 63, wave = t >> 6;
  const int lrow = lane & 15, lq = lane >> 4;
  const int wstrip = wave * 32;

  // D[d][w] = sum_c WsT[d][c] * Os[w][c]; A fragments straight from global (L2-hot)
  f32x4 acc[8][2];
#pragma unroll
  for (int mt = 0; mt < 8; ++mt) {
    acc[mt][0] = (f32x4){0.f, 0.f, 0.f, 0.f};
    acc[mt][1] = (f32x4){0.f, 0.f, 0.f, 0.f};
  }
#pragma unroll
  for (int kk = 0; kk < 4; ++kk) {
    int ko = kk * 32 + lq * 8;
    bf16x8 b0 = *(const bf16x8*)&Os[TIDX(wstrip + lrow, ko)];
    bf16x8 b1 = *(const bf16x8*)&Os[TIDX(wstrip + 16 + lrow, ko)];
#pragma unroll
    for (int mt = 0; mt < 8; ++mt) {
      bf16x8 a = *(const bf16x8*)&wsT[(mt * 16 + lrow) * 128 + ko];
      acc[mt][0] = MFMA(a, b0, acc[mt][0]);
      acc[mt][1] = MFMA(a, b1, acc[mt][1]);
    }
  }

  // fused epilogue: sigmoid + BN + gated residual, direct coalesced f32x4 I/O
#pragma unroll
  for (int mt = 0; mt < 8; ++mt) {
    int d0 = mt * 16 + lq * 4;
    f32x4 A4 = *(const f32x4*)&bnA[d0];
    f32x4 B4 = *(const f32x4*)&bnB[d0];
    f32x4 S4 = *(const f32x4*)&bsf[d0];
#pragma unroll
    for (int nt = 0; nt < 2; ++nt) {
      int w = wstrip + nt * 16 + lrow;
      size_t off = pixbase + (size_t)w * 128 + d0;
      f32x4 a1v = *(const f32x4*)&x1[off];
      f32x4 a2v = *(const f32x4*)&x2[off];
      f32x4 r;
#pragma unroll
      for (int r4 = 0; r4 < 4; ++r4) {
        float sv = acc[mt][nt][r4] + S4[r4];
        float sg = 1.f / (1.f + __expf(-sv));
        float g = A4[r4] * sg + B4[r4];
        r[r4] = a1v[r4] + a2v[r4] * g;
      }
      *(f32x4*)&out[off] = r;
    }
  }
}

extern "C" void kernel_launch(void* const* d_in, const int* in_sizes, int n_in,
                              void* d_out, int out_size, void* d_ws, size_t ws_size,
                              hipStream_t stream) {
  const float* x1 = (const float*)d_in[0];
  const float* x2 = (const float*)d_in[1];
  const float* Wq = (const float*)d_in[2];
  const float* Wk = (const float*)d_in[3];
  const float* Wv = (const float*)d_in[4];
  const float* Ws = (const float*)d_in[5];
  const float* bs = (const float*)d_in[6];
  const float* scale = (const float*)d_in[7];
  const float* gamma = (const float*)d_in[8];
  const float* beta = (const float*)d_in[9];
  const float* mu = (const float*)d_in[10];
  const float* var = (const float*)d_in[11];
  float* outp = (float*)d_out;

  // workspace: q8|k8|v8 fp8 [B][C][H][W] (16MB each), o16 bf16 (32MB), wT (128KB)
  u8* q8 = (u8*)d_ws;
  u8* k8 = q8 + 16777216;
  u8* v8 = k8 + 16777216;
  u16* o16 = (u16*)(v8 + 16777216);
  u16* wT = (u16*)((u8*)o16 + 33554432);

  wprep<<<dim3(4), dim3(256), 0, stream>>>(Wq, Wk, Wv, Ws, wT);
  qkv_kernel<<<dim3(3072), dim3(256), 0, stream>>>(x1, x2, wT, q8, k8, v8);
  attn_kernel<<<dim3(1024), dim3(256), 0, stream>>>(q8, k8, v8, o16, scale);
  final_kernel<<<dim3(1024), dim3(256), 0, stream>>>(o16, wT + 3 * 16384, x1, x2, bs,
                                                     gamma, beta, mu, var, outp);
}

// Round 12
// 307.488 us; speedup vs baseline: 1.1338x; 1.0277x over previous
//
#include <hip/hip_runtime.h>

typedef unsigned int u32;
typedef unsigned short u16;
typedef unsigned char u8;
typedef u16 u16x4 __attribute__((ext_vector_type(4)));
typedef u16 u16x8 __attribute__((ext_vector_type(8)));
typedef u32 u32x2 __attribute__((ext_vector_type(2)));
typedef u32 u32x4 __attribute__((ext_vector_type(4)));
typedef __bf16 bf16x8 __attribute__((ext_vector_type(8)));
typedef float f32x2 __attribute__((ext_vector_type(2)));
typedef float f32x4 __attribute__((ext_vector_type(4)));
typedef long long i64;

#define LDK 136   // padded LDS leading dim (qkv stage / final): 4-bank shift per row
#define TIDX(r, c) ((r) * LDK + ((c) ^ (((r) & 3) << 5)))
// attn V^T/O phase: 32KB linear u16 tile, 16B-chunk XOR swizzle (r4-proven)
#define TIDX8(r, c) ((r) * 128 + ((c) ^ (((r) & 7) << 3)))
#define MFMA(a, b, c) __builtin_amdgcn_mfma_f32_16x16x32_bf16(a, b, c, 0, 0, 0)
#define MFMA8(a, b, c) __builtin_amdgcn_mfma_f32_16x16x32_fp8_fp8(a, b, c, 0, 0, 0)

__device__ __forceinline__ u16 f2b(float f) {
  u32 u = __builtin_bit_cast(u32, f);
  u = (u + 0x7fffu + ((u >> 16) & 1u)) >> 16;
  return (u16)u;
}
__device__ __forceinline__ u32 pk2(float lo, float hi) {
  return (u32)f2b(lo) | ((u32)f2b(hi) << 16);
}
// 4 floats -> 4 fp8 e4m3 bytes (w order preserved)
__device__ __forceinline__ u32 pk4f8(float a, float b, float c, float d) {
  int v = __builtin_amdgcn_cvt_pk_fp8_f32(a, b, 0, false);
  v = __builtin_amdgcn_cvt_pk_fp8_f32(c, d, v, true);
  return (u32)v;
}
// async global->LDS 16B: per-lane global src, wave-uniform LDS base + lane*16
__device__ __forceinline__ void gl2lds16(const void* g, void* l) {
  __builtin_amdgcn_global_load_lds(
      (const __attribute__((address_space(1))) unsigned int*)g,
      (__attribute__((address_space(3))) unsigned int*)l, 16, 0, 0);
}

// ---------------- weight prep: wT[m][d][c] = bf16(W_m[c][d]) ----------------
__global__ void wprep(const float* __restrict__ Wq, const float* __restrict__ Wk,
                      const float* __restrict__ Wv, const float* __restrict__ Ws,
                      u16* __restrict__ wT) {
  const float* srcs[4] = {Wq, Wk, Wv, Ws};
  const float* s = srcs[blockIdx.x];
  u16* d = wT + (size_t)blockIdx.x * 16384;
  for (int idx = threadIdx.x; idx < 16384; idx += 256) {
    int i = idx >> 7, j = idx & 127;   // W[i=c_in][j=c_out]
    d[j * 128 + i] = f2b(s[idx]);
  }
}

// ---------------- QKV: bf16 GEMM (r7-proven) + fp8 output pack ----------------
__global__ __launch_bounds__(256, 4)
void qkv_kernel(const float* __restrict__ x1, const float* __restrict__ x2,
                const u16* __restrict__ wT,
                u8* __restrict__ q8, u8* __restrict__ k8, u8* __restrict__ v8) {
  __shared__ u16 Xs[128 * LDK];   // stage [w][c] bf16; later u8 bounce tile (18KB)

  const int t = threadIdx.x;
  const int bid = blockIdx.x;
  const int xs = bid & 7;
  const int m = (bid >> 3) % 3;            // 0=q, 1=k, 2=v
  const int bh = (bid / 24) * 8 + xs;      // each (bh,m) exactly once; XCD-grouped
  const int b = bh >> 7, h = bh & 127;
  const size_t pixbase = (size_t)bh * 16384;
  const size_t obase8 = (size_t)b * 2097152 + (size_t)h * 128;   // bytes

  const float* xin = (m == 2) ? x2 : x1;
  u8* dst = (m == 0) ? q8 : (m == 1) ? k8 : v8;

  const int lane = t & 63, wave = t >> 6;
  const int lrow = lane & 15, lq = lane >> 4;
  const int nstrip = wave * 32;

  // stage x row-tile -> Xs[w][c] bf16 (swizzled)
#pragma unroll
  for (int j = 0; j < 8; ++j) {
    int lin = j * 256 + t;
    int w = lin >> 4, c0 = (lin & 15) << 3;
    f32x4 a0 = *(const f32x4*)&xin[pixbase + lin * 8];
    f32x4 a1 = *(const f32x4*)&xin[pixbase + lin * 8 + 4];
    u16x8 p;
#pragma unroll
    for (int i = 0; i < 4; ++i) { p[i] = f2b(a0[i]); p[4 + i] = f2b(a1[i]); }
    *(u16x8*)&Xs[TIDX(w, c0)] = p;
  }

  // B fragments straight from global (L2-hot)
  const u16* wb = wT + (size_t)m * 16384;
  bf16x8 w0[4], w1[4];
#pragma unroll
  for (int kk = 0; kk < 4; ++kk) {
    int ko = kk * 32 + lq * 8;
    w0[kk] = *(const bf16x8*)&wb[(nstrip + lrow) * 128 + ko];
    w1[kk] = *(const bf16x8*)&wb[(nstrip + 16 + lrow) * 128 + ko];
  }
  __syncthreads();

  f32x4 acc[8][2];
#pragma unroll
  for (int mt = 0; mt < 8; ++mt) {
    acc[mt][0] = (f32x4){0.f, 0.f, 0.f, 0.f};
    acc[mt][1] = (f32x4){0.f, 0.f, 0.f, 0.f};
  }
#pragma unroll
  for (int kk = 0; kk < 4; ++kk) {
    int ko = kk * 32 + lq * 8;
#pragma unroll
    for (int mt = 0; mt < 8; ++mt) {
      bf16x8 a = *(const bf16x8*)&Xs[TIDX(mt * 16 + lrow, ko)];
      acc[mt][0] = MFMA(a, w0[kk], acc[mt][0]);
      acc[mt][1] = MFMA(a, w1[kk], acc[mt][1]);
    }
  }
  __syncthreads();   // all GEMM reads of Xs done -> reuse as u8 bounce tile

  // bounce: relu(acc) -> fp8 -> Xs8[c][w] (pitch 144B)
  u8* Xs8 = (u8*)Xs;
#pragma unroll
  for (int mt = 0; mt < 8; ++mt) {
    int w0i = mt * 16 + lq * 4;   // byte offset (1B/elem)
#pragma unroll
    for (int nt = 0; nt < 2; ++nt) {
      int c = nstrip + nt * 16 + lrow;
      u32 p = pk4f8(fmaxf(acc[mt][nt][0], 0.f), fmaxf(acc[mt][nt][1], 0.f),
                    fmaxf(acc[mt][nt][2], 0.f), fmaxf(acc[mt][nt][3], 0.f));
      *(u32*)&Xs8[c * 144 + w0i] = p;
    }
  }
  __syncthreads();

  // coalesced store: per j, 8 c-rows x 128B (full lines)
#pragma unroll
  for (int j = 0; j < 4; ++j) {
    int c = j * 32 + (t >> 3), bo = (t & 7) * 16;
    u32x4 v = *(const u32x4*)&Xs8[c * 144 + bo];
    *(u32x4*)&dst[obase8 + (size_t)c * 16384 + bo] = v;
  }
}

// ---------------- attention: fp8 QK^T, bf16 softmax/PV; O -> o_t (bf16) ------------
__global__ __launch_bounds__(256, 4)
void attn_kernel(const u8* __restrict__ q8, const u8* __restrict__ k8,
                 const u8* __restrict__ v8, u16* __restrict__ o16,
                 const float* __restrict__ scale_p) {
  __shared__ u16 Ks[128 * 128];   // K phase: low 16KB as u8; later V^T/O bf16 tile
  u8* Ks8 = (u8*)Ks;

  const int t = threadIdx.x;
  const size_t base8 = (size_t)blockIdx.x * 16384;    // bytes (fp8 plane)
  const size_t base16 = (size_t)blockIdx.x * 16384;   // u16 elems (o plane)

  const int lane = t & 63, wave = t >> 6;
  const int lrow = lane & 15, lq = lane >> 4;
  const int hstrip = wave * 32;
  const float scl = scale_p[0];
  const int swl = (lrow & 7) << 4;   // per-lane K source/read swizzle

  // K stage: async DMA, linear LDS dest; swizzle folded into SOURCE address
#pragma unroll
  for (int j = 0; j < 4; ++j) {
    int lin = j * 256 + t;
    int r = lin >> 3, c16 = (lin & 7) << 4;
    gl2lds16(&k8[base8 + r * 128 + (c16 ^ ((r & 7) << 4))],
             &Ks8[(size_t)(j * 256 + (t & 192)) * 16]);
  }

  // Q fragments (fp8, 8B each) straight from global
  i64 q0[4], q1[4];
#pragma unroll
  for (int kk = 0; kk < 4; ++kk) {
    int ko = kk * 32 + lq * 8;
    q0[kk] = *(const i64*)&q8[base8 + (hstrip + lrow) * 128 + ko];
    q1[kk] = *(const i64*)&q8[base8 + (hstrip + 16 + lrow) * 128 + ko];
  }
  __syncthreads();   // drains gload_lds

  // S^T[g][h]: A = K fp8 rows g, B = Q fp8 frags
  f32x4 acc[8][2];
#pragma unroll
  for (int mt = 0; mt < 8; ++mt) {
    acc[mt][0] = (f32x4){0.f, 0.f, 0.f, 0.f};
    acc[mt][1] = (f32x4){0.f, 0.f, 0.f, 0.f};
  }
#pragma unroll
  for (int kk = 0; kk < 4; ++kk) {
    int ko = kk * 32 + lq * 8;
#pragma unroll
    for (int mt = 0; mt < 8; ++mt) {
      i64 a = *(const i64*)&Ks8[(mt * 16 + lrow) * 128 + (ko ^ swl)];
      acc[mt][0] = MFMA8(a, q0[kk], acc[mt][0]);
      acc[mt][1] = MFMA8(a, q1[kk], acc[mt][1]);
    }
  }

  // V loads (fp8, coalesced 128B runs); latency hides under softmax+pack
  const int w0v = (t & 15) * 8, g0 = (t >> 4) * 8;
  u32x2 vv[8];
#pragma unroll
  for (int i = 0; i < 8; ++i)
    vv[i] = *(const u32x2*)&v8[base8 + (size_t)(g0 + i) * 128 + w0v];

  // softmax over g: per-lane 32 values + quad combine via shfl_xor 16/32
  float inv[2];
#pragma unroll
  for (int nt = 0; nt < 2; ++nt) {
    float mx = -1e30f;
#pragma unroll
    for (int mt = 0; mt < 8; ++mt)
#pragma unroll
      for (int r = 0; r < 4; ++r) {
        acc[mt][nt][r] *= scl;
        mx = fmaxf(mx, acc[mt][nt][r]);
      }
    mx = fmaxf(mx, __shfl_xor(mx, 16));
    mx = fmaxf(mx, __shfl_xor(mx, 32));
    float s = 0.f;
#pragma unroll
    for (int mt = 0; mt < 8; ++mt)
#pragma unroll
      for (int r = 0; r < 4; ++r) {
        float e = __expf(acc[mt][nt][r] - mx);
        acc[mt][nt][r] = e;
        s += e;
      }
    s += __shfl_xor(s, 16);
    s += __shfl_xor(s, 32);
    inv[nt] = 1.f / s;
  }

  // pack P (with 1/sum folded) into registers: pk[mt][nt][pair] (bf16 pairs)
  u32 pk[8][2][2];
#pragma unroll
  for (int mt = 0; mt < 8; ++mt)
#pragma unroll
    for (int nt = 0; nt < 2; ++nt) {
      pk[mt][nt][0] = pk2(acc[mt][nt][0] * inv[nt], acc[mt][nt][1] * inv[nt]);
      pk[mt][nt][1] = pk2(acc[mt][nt][2] * inv[nt], acc[mt][nt][3] * inv[nt]);
    }
  __syncthreads();   // all S-MFMA reads of K complete -> K dead

  // V expand fp8->bf16 (per row), then 8x8 transpose into Ks[TIDX8] (static idx)
  u16x8 bb[8];
#pragma unroll
  for (int i = 0; i < 8; ++i) {
    f32x2 p0 = __builtin_amdgcn_cvt_pk_f32_fp8((int)vv[i][0], false);
    f32x2 p1 = __builtin_amdgcn_cvt_pk_f32_fp8((int)vv[i][0], true);
    f32x2 p2 = __builtin_amdgcn_cvt_pk_f32_fp8((int)vv[i][1], false);
    f32x2 p3 = __builtin_amdgcn_cvt_pk_f32_fp8((int)vv[i][1], true);
    bb[i][0] = f2b(p0[0]); bb[i][1] = f2b(p0[1]);
    bb[i][2] = f2b(p1[0]); bb[i][3] = f2b(p1[1]);
    bb[i][4] = f2b(p2[0]); bb[i][5] = f2b(p2[1]);
    bb[i][6] = f2b(p3[0]); bb[i][7] = f2b(p3[1]);
  }
#pragma unroll
  for (int j = 0; j < 8; ++j) {
    u16x8 tv;
#pragma unroll
    for (int i = 0; i < 8; ++i) tv[i] = bb[i][j];
    *(u16x8*)&Ks[TIDX8(w0v + j, g0)] = tv;
  }
  __syncthreads();

  // O^T[w][h]: A = Ks(V^T bf16) rows w, B = P via shfl redistribution
  const int s01 = lrow + 32 * (lq & 1);
  const int s23 = s01 + 16;
  const bool hi = (lq & 2);
#pragma unroll
  for (int kk = 0; kk < 4; ++kk) {
    int ko = kk * 32 + lq * 8;
    u32x4 bd[2];
#pragma unroll
    for (int nt = 0; nt < 2; ++nt) {
      u32 a0 = pk[2 * kk][nt][0], a1 = pk[2 * kk][nt][1];
      u32 c0 = pk[2 * kk + 1][nt][0], c1 = pk[2 * kk + 1][nt][1];
      u32 l0 = (u32)__shfl((int)a0, s01), h0 = (u32)__shfl((int)c0, s01);
      u32 l1 = (u32)__shfl((int)a1, s01), h1 = (u32)__shfl((int)c1, s01);
      u32 l2 = (u32)__shfl((int)a0, s23), h2 = (u32)__shfl((int)c0, s23);
      u32 l3 = (u32)__shfl((int)a1, s23), h3 = (u32)__shfl((int)c1, s23);
      bd[nt][0] = hi ? h0 : l0;
      bd[nt][1] = hi ? h1 : l1;
      bd[nt][2] = hi ? h2 : l2;
      bd[nt][3] = hi ? h3 : l3;
    }
    bf16x8 bb0 = __builtin_bit_cast(bf16x8, bd[0]);
    bf16x8 bb1 = __builtin_bit_cast(bf16x8, bd[1]);
    if (kk == 0) {
#pragma unroll
      for (int mt = 0; mt < 8; ++mt) {
        acc[mt][0] = (f32x4){0.f, 0.f, 0.f, 0.f};
        acc[mt][1] = (f32x4){0.f, 0.f, 0.f, 0.f};
      }
    }
#pragma unroll
    for (int mt = 0; mt < 8; ++mt) {
      bf16x8 a = *(const bf16x8*)&Ks[TIDX8(mt * 16 + lrow, ko)];
      acc[mt][0] = MFMA(a, bb0, acc[mt][0]);
      acc[mt][1] = MFMA(a, bb1, acc[mt][1]);
    }
  }
  __syncthreads();   // PV reads of Ks done -> reuse as O bounce tile

  // bounce O -> Ks[h][w] (bf16), then fully-contiguous store to o_t
#pragma unroll
  for (int mt = 0; mt < 8; ++mt) {
    int w0i = mt * 16 + lq * 4;
#pragma unroll
    for (int nt = 0; nt < 2; ++nt) {
      int hh = hstrip + nt * 16 + lrow;
      u32x2 p;
      p[0] = pk2(acc[mt][nt][0], acc[mt][nt][1]);
      p[1] = pk2(acc[mt][nt][2], acc[mt][nt][3]);
      *(u32x2*)&Ks[TIDX8(hh, w0i)] = p;
    }
  }
  __syncthreads();
#pragma unroll
  for (int j = 0; j < 8; ++j) {
    int hh = j * 16 + (t >> 4), wv = (t & 15) * 8;
    *(u16x8*)&o16[base16 + hh * 128 + wv] = *(const u16x8*)&Ks[TIDX8(hh, wv)];
  }
}

// ---------------- final: s = o @ Ws + bs; sigmoid; BN; out = x1 + x2*g --------------
// Epilogue software-pipelined depth-4: x1/x2 loads issue 4 iterations ahead
// (named buffers, compile-time idx under full unroll — rule #20 safe).
__global__ __launch_bounds__(256, 4)
void final_kernel(const u16* __restrict__ o_t, const u16* __restrict__ wsT,
                  const float* __restrict__ x1, const float* __restrict__ x2,
                  const float* __restrict__ bs, const float* __restrict__ gamma,
                  const float* __restrict__ beta, const float* __restrict__ mu,
                  const float* __restrict__ var, float* __restrict__ out) {
  __shared__ u16 Os[128 * LDK];   // o^T tile [w][c] (swizzled)
  __shared__ float bnA[128], bnB[128], bsf[128];

  const int t = threadIdx.x;
  const int bh = blockIdx.x;
  const int b = bh >> 7, h = bh & 127;
  const size_t obase = (size_t)b * 2097152 + (size_t)h * 128;
  const size_t pixbase = (size_t)bh * 16384;

  if (t < 128) {
    float a = gamma[t] * rsqrtf(var[t] + 1e-3f);
    bnA[t] = a;
    bnB[t] = beta[t] - mu[t] * a;
    bsf[t] = bs[t];
  }
  {  // coalesced transpose-load o tile -> Os[w][c] (static indexing only)
    int cb = (t >> 4) * 8, w0 = (t & 15) * 8;
    u16 ov[8][8];
#pragma unroll
    for (int i = 0; i < 8; ++i)
      *(u16x8*)&ov[i][0] = *(const u16x8*)&o_t[obase + (size_t)(cb + i) * 16384 + w0];
#pragma unroll
    for (int j = 0; j < 8; ++j) {
      u16x8 tv;
#pragma unroll
      for (int i = 0; i < 8; ++i) tv[i] = ov[i][j];
      *(u16x8*)&Os[TIDX(w0 + j, cb)] = tv;
    }
  }
  __syncthreads();

  const int lane = t & 63, wave = t >> 6;
  const int lrow = lane & 15, lq = lane >> 4;
  const int wstrip = wave * 32;

  // D[d][w] = sum_c WsT[d][c] * Os[w][c]; A fragments straight from global (L2-hot)
  f32x4 acc[8][2];
#pragma unroll
  for (int mt = 0; mt < 8; ++mt) {
    acc[mt][0] = (f32x4){0.f, 0.f, 0.f, 0.f};
    acc[mt][1] = (f32x4){0.f, 0.f, 0.f, 0.f};
  }
#pragma unroll
  for (int kk = 0; kk < 4; ++kk) {
    int ko = kk * 32 + lq * 8;
    bf16x8 b0 = *(const bf16x8*)&Os[TIDX(wstrip + lrow, ko)];
    bf16x8 b1 = *(const bf16x8*)&Os[TIDX(wstrip + 16 + lrow, ko)];
#pragma unroll
    for (int mt = 0; mt < 8; ++mt) {
      bf16x8 a = *(const bf16x8*)&wsT[(mt * 16 + lrow) * 128 + ko];
      acc[mt][0] = MFMA(a, b0, acc[mt][0]);
      acc[mt][1] = MFMA(a, b1, acc[mt][1]);
    }
  }

  // epilogue, depth-4 pipelined: it = mt*2+nt; off = pixbase + w*128 + d0
  f32x4 va[4], vb[4];
#pragma unroll
  for (int p = 0; p < 4; ++p) {
    int d0 = (p >> 1) * 16 + lq * 4;
    int w = wstrip + (p & 1) * 16 + lrow;
    size_t off = pixbase + (size_t)w * 128 + d0;
    va[p] = *(const f32x4*)&x1[off];
    vb[p] = *(const f32x4*)&x2[off];
  }
#pragma unroll
  for (int it = 0; it < 16; ++it) {
    const int mt = it >> 1, nt = it & 1;
    const int d0 = mt * 16 + lq * 4;
    const int w = wstrip + nt * 16 + lrow;
    const size_t off = pixbase + (size_t)w * 128 + d0;
    f32x4 A4 = *(const f32x4*)&bnA[d0];
    f32x4 B4 = *(const f32x4*)&bnB[d0];
    f32x4 S4 = *(const f32x4*)&bsf[d0];
    f32x4 a1v = va[it & 3], a2v = vb[it & 3];
    f32x4 r;
#pragma unroll
    for (int r4 = 0; r4 < 4; ++r4) {
      float sv = acc[mt][nt][r4] + S4[r4];
      float sg = 1.f / (1.f + __expf(-sv));
      float g = A4[r4] * sg + B4[r4];
      r[r4] = a1v[r4] + a2v[r4] * g;
    }
    *(f32x4*)&out[off] = r;
    if (it + 4 < 16) {
      const int p = it + 4;
      const int pd0 = (p >> 1) * 16 + lq * 4;
      const int pw = wstrip + (p & 1) * 16 + lrow;
      const size_t poff = pixbase + (size_t)pw * 128 + pd0;
      va[it & 3] = *(const f32x4*)&x1[poff];
      vb[it & 3] = *(const f32x4*)&x2[poff];
    }
  }
}

extern "C" void kernel_launch(void* const* d_in, const int* in_sizes, int n_in,
                              void* d_out, int out_size, void* d_ws, size_t ws_size,
                              hipStream_t stream) {
  const float* x1 = (const float*)d_in[0];
  const float* x2 = (const float*)d_in[1];
  const float* Wq = (const float*)d_in[2];
  const float* Wk = (const float*)d_in[3];
  const float* Wv = (const float*)d_in[4];
  const float* Ws = (const float*)d_in[5];
  const float* bs = (const float*)d_in[6];
  const float* scale = (const float*)d_in[7];
  const float* gamma = (const float*)d_in[8];
  const float* beta = (const float*)d_in[9];
  const float* mu = (const float*)d_in[10];
  const float* var = (const float*)d_in[11];
  float* outp = (float*)d_out;

  // workspace: q8|k8|v8 fp8 [B][C][H][W] (16MB each), o16 bf16 (32MB), wT (128KB)
  u8* q8 = (u8*)d_ws;
  u8* k8 = q8 + 16777216;
  u8* v8 = k8 + 16777216;
  u16* o16 = (u16*)(v8 + 16777216);
  u16* wT = (u16*)((u8*)o16 + 33554432);

  wprep<<<dim3(4), dim3(256), 0, stream>>>(Wq, Wk, Wv, Ws, wT);
  qkv_kernel<<<dim3(3072), dim3(256), 0, stream>>>(x1, x2, wT, q8, k8, v8);
  attn_kernel<<<dim3(1024), dim3(256), 0, stream>>>(q8, k8, v8, o16, scale);
  final_kernel<<<dim3(1024), dim3(256), 0, stream>>>(o16, wT + 3 * 16384, x1, x2, bs,
                                                     gamma, beta, mu, var, outp);
}